// Round 4
// baseline (400.149 us; speedup 1.0000x reference)
//
#include <hip/hip_runtime.h>
#include <hip/hip_bf16.h>

typedef __hip_bfloat16 bf16;
typedef __bf16 bf16x8 __attribute__((ext_vector_type(8)));  // MFMA A/B operand
typedef float f32x4 __attribute__((ext_vector_type(4)));

constexpr int Bn = 8, Sn = 2048, Dn = 1024;
constexpr int BM = 256, BN = 256, BK = 64;

// ---------------- cast fp32 -> bf16, vectorized ----------------
__global__ void cast_f32_bf16_k(const float* __restrict__ x, bf16* __restrict__ y, int n) {
  int i = (blockIdx.x * blockDim.x + threadIdx.x) * 4;
  if (i >= n) return;
  float4 f = *reinterpret_cast<const float4*>(x + i);
  bf16 tmp[4] = {__float2bfloat16(f.x), __float2bfloat16(f.y),
                 __float2bfloat16(f.z), __float2bfloat16(f.w)};
  *reinterpret_cast<short4*>(y + i) = *reinterpret_cast<const short4*>(tmp);
}

// ---------------- transpose+cast V: [B][S][D] f32 -> [B][D][S] bf16 ----------------
__global__ void transpose_cast_v_k(const float* __restrict__ v, bf16* __restrict__ vt) {
  __shared__ float tile[32][33];
  const int s0 = blockIdx.x * 32, d0 = blockIdx.y * 32, b = blockIdx.z;
  const float* src = v + (size_t)b * Sn * Dn;
  bf16* dst = vt + (size_t)b * Dn * Sn;
  const int tx = threadIdx.x & 31, ty = threadIdx.x >> 5;
  #pragma unroll
  for (int i = 0; i < 4; ++i) {
    int s = ty + i * 8;
    tile[s][tx] = src[(size_t)(s0 + s) * Dn + d0 + tx];
  }
  __syncthreads();
  #pragma unroll
  for (int i = 0; i < 4; ++i) {
    int d = ty + i * 8;
    dst[(size_t)(d0 + d) * Sn + s0 + tx] = __float2bfloat16(tile[tx][d]);
  }
}

// ---------------- 256x256x64 8-phase GEMM (m201 schedule): C = A @ BT^T ----------------
// LDS element map: A0=0  A1=16384  B0=32768  B1=49152 (each 32KB region, 2 halves)
#define SBAR()  asm volatile("s_barrier" ::: "memory")
#define LGKM0() asm volatile("s_waitcnt lgkmcnt(0)" ::: "memory")
#define VM4()   asm volatile("s_waitcnt vmcnt(4)" ::: "memory")
#define VM0()   asm volatile("s_waitcnt vmcnt(0)" ::: "memory")

// builtin MFMA cluster: compiler owns scheduling + AV register allocation
#define QUAD(ms, ns) do {                                                     \
    __builtin_amdgcn_s_setprio(1);                                            \
    _Pragma("unroll")                                                         \
    for (int kk = 0; kk < 2; ++kk)                                            \
      _Pragma("unroll")                                                       \
      for (int mi4 = 0; mi4 < 4; ++mi4)                                       \
        _Pragma("unroll")                                                     \
        for (int n2 = 0; n2 < 2; ++n2)                                        \
          acc[(ms)*4+mi4][(ns)*2+n2] =                                        \
            __builtin_amdgcn_mfma_f32_16x16x32_bf16(                          \
              aF[mi4][kk], bF[(ns)*2+n2][kk],                                 \
              acc[(ms)*4+mi4][(ns)*2+n2], 0, 0, 0);                           \
    __builtin_amdgcn_s_setprio(0);                                            \
  } while (0)

#define RD_A(buf, ms) do {                                                    \
    _Pragma("unroll")                                                         \
    for (int mi4 = 0; mi4 < 4; ++mi4) {                                       \
      aF[mi4][0] = rdA(buf, ms, mi4, 0);                                      \
      aF[mi4][1] = rdA(buf, ms, mi4, 1);                                      \
    }                                                                         \
  } while (0)

#define RD_B(buf, ns) do {                                                    \
    bF[(ns)*2  ][0] = rdB(buf, ns, 0, 0);                                     \
    bF[(ns)*2  ][1] = rdB(buf, ns, 0, 1);                                     \
    bF[(ns)*2+1][0] = rdB(buf, ns, 1, 0);                                     \
    bF[(ns)*2+1][1] = rdB(buf, ns, 1, 1);                                     \
  } while (0)

template<int EPI>
__global__ __launch_bounds__(512, 2)
void gemm256_k(const bf16* __restrict__ A, const bf16* __restrict__ BT,
               void* __restrict__ Cv, const float* __restrict__ aux,
               int N, int K, long long sAz, long long sBz, long long sCz,
               float scale, int gx, int gy)
{
  __shared__ __align__(128) bf16 sh[4 * 16384];   // 128 KiB

  // T1: XCD-aware bijective swizzle (nwg % 8 == 0 for all launches here)
  const int nwg = (int)gridDim.x;
  const int flat = (int)blockIdx.x;
  const int swz = (flat & 7) * (nwg >> 3) + (flat >> 3);
  const int tn = swz % gx;
  const int rem = swz / gx;
  const int tm = rem % gy;
  const int z  = rem / gy;

  const int t = threadIdx.x, w = t >> 6, lane = t & 63;
  const int wm = w >> 2, wn = w & 3;              // 2 x 4 wave grid; wave tile 128x64
  const int fr = lane & 15, kg = lane >> 4;
  const int m0 = tm * BM, n0 = tn * BN;
  const bf16* Abase = A + (size_t)z * sAz + (size_t)m0 * K;
  const bf16* Bbase = BT + (size_t)z * sBz + (size_t)n0 * K;

  f32x4 acc[8][4];
  const f32x4 fz = {0.f, 0.f, 0.f, 0.f};
  #pragma unroll
  for (int i = 0; i < 8; ++i)
    #pragma unroll
    for (int j = 0; j < 4; ++j) acc[i][j] = fz;
  bf16x8 aF[4][2], bF[4][2];

  // stage one half-tile (128 rows x 64 cols): linear LDS dest + source-swizzled cols
  auto stage = [&](int dstElemBase, const bf16* gbase, int half, int kt) {
    const bf16* g0 = gbase + (size_t)(half * 128) * K + (size_t)kt * BK;
    bf16* db = (bf16*)sh + dstElemBase + half * 8192;
    #pragma unroll
    for (int i = 0; i < 2; ++i) {
      const int s0 = i * 512 + w * 64;
      const int slot = s0 + lane;
      const int row = slot >> 3;
      const int cb = (slot & 7) ^ (row & 7);       // inverse of read-side XOR swizzle
      const bf16* src = g0 + (size_t)row * K + cb * 8;
      __builtin_amdgcn_global_load_lds((__attribute__((address_space(1))) void*)src,
          (__attribute__((address_space(3))) void*)(db + s0 * 8), 16, 0, 0);
    }
  };
  // swizzled fragment reads (ds_read_b128); tile-local byte ^= (row&7)<<4
  auto rdA = [&](int buf, int ms, int mi4, int kk) -> bf16x8 {
    const int row = wm * 128 + ms * 64 + mi4 * 16 + fr;
    int loc = row * 128 + kk * 64 + kg * 16;
    loc ^= (row & 7) << 4;
    return *reinterpret_cast<const bf16x8*>((const char*)sh + buf * 32768 + loc);
  };
  auto rdB = [&](int buf, int ns, int j, int kk) -> bf16x8 {
    const int row = wn * 64 + ns * 32 + j * 16 + fr;
    int loc = row * 128 + kk * 64 + kg * 16;
    loc ^= (row & 7) << 4;
    return *reinterpret_cast<const bf16x8*>((const char*)sh + 65536 + buf * 32768 + loc);
  };

  const int NT = K / BK;                          // even, >= 4
  // prologue: tile0 full + tile1 B (12 loads/thread); drain tile0 (leave tile1-B in flight)
  stage(32768, Bbase, 0, 0); stage(32768, Bbase, 1, 0);
  stage(0,     Abase, 0, 0); stage(0,     Abase, 1, 0);
  stage(49152, Bbase, 0, 1); stage(49152, Bbase, 1, 1);
  VM4();
  SBAR();

  for (int T = 0; T < NT; T += 2) {
    const bool last = (T + 2 >= NT);
    // ph1: compute T quadrant (0,0); stage A1-lo (tile T+1)
    RD_A(0, 0); RD_B(0, 0);
    stage(16384, Abase, 0, T + 1);
    SBAR(); LGKM0(); QUAD(0, 0); SBAR();
    // ph2: quadrant (0,1); stage A1-hi (T+1)
    RD_B(0, 1);
    stage(16384, Abase, 1, T + 1);
    SBAR(); LGKM0(); QUAD(0, 1); SBAR();
    // ph3: quadrant (1,0); stage B0-lo (T+2)  [B0 free after ph2]
    RD_A(0, 1);
    if (!last) stage(32768, Bbase, 0, T + 2);
    SBAR(); LGKM0(); QUAD(1, 0); SBAR();
    // ph4: quadrant (1,1); stage B0-hi (T+2); drain tile T+1 before its reads in ph5
    if (!last) stage(32768, Bbase, 1, T + 2);
    SBAR(); LGKM0(); QUAD(1, 1);
    if (last) { VM0(); } else { VM4(); }
    SBAR();
    // ph5: tile T+1 quadrant (0,0); stage A0-lo (T+2)  [A0 free after ph3]
    RD_A(1, 0); RD_B(1, 0);
    if (!last) stage(0, Abase, 0, T + 2);
    SBAR(); LGKM0(); QUAD(0, 0); SBAR();
    // ph6: quadrant (0,1); stage A0-hi (T+2)
    RD_B(1, 1);
    if (!last) stage(0, Abase, 1, T + 2);
    SBAR(); LGKM0(); QUAD(0, 1); SBAR();
    // ph7: quadrant (1,0); stage B1-lo (T+3)  [B1 free after ph6]
    RD_A(1, 1);
    if (!last) stage(49152, Bbase, 0, T + 3);
    SBAR(); LGKM0(); QUAD(1, 0); SBAR();
    // ph8: quadrant (1,1); stage B1-hi (T+3); drain tile T+2 before next ph1
    if (!last) stage(49152, Bbase, 1, T + 3);
    SBAR(); LGKM0(); QUAD(1, 1);
    if (!last) { VM4(); }
    SBAR();
  }

  // epilogue: frag (mi,ni): C[m0+wm*128+mi*16+kg*4+r][n0+wn*64+ni*16+fr]
  const int or0 = kg * 4;
  if constexpr (EPI == 0) {
    bf16* C = (bf16*)Cv + (size_t)z * sCz;
    #pragma unroll
    for (int mi = 0; mi < 8; ++mi)
      #pragma unroll
      for (int r = 0; r < 4; ++r) {
        const int row = m0 + wm * 128 + mi * 16 + or0 + r;
        #pragma unroll
        for (int ni = 0; ni < 4; ++ni) {
          const int col = n0 + wn * 64 + ni * 16 + fr;
          C[(size_t)row * N + col] = __float2bfloat16(acc[mi][ni][r] + aux[col]);
        }
      }
  } else if constexpr (EPI == 1) {
    bf16* C = (bf16*)Cv + (size_t)z * sCz;
    #pragma unroll
    for (int mi = 0; mi < 8; ++mi)
      #pragma unroll
      for (int r = 0; r < 4; ++r) {
        const int row = m0 + wm * 128 + mi * 16 + or0 + r;
        #pragma unroll
        for (int ni = 0; ni < 4; ++ni) {
          const int col = n0 + wn * 64 + ni * 16 + fr;
          float v = acc[mi][ni][r] * scale + aux[(size_t)row * N + col];
          C[(size_t)row * N + col] = __float2bfloat16(v);
        }
      }
  } else {
    float* C = (float*)Cv + (size_t)z * sCz;
    #pragma unroll
    for (int mi = 0; mi < 8; ++mi)
      #pragma unroll
      for (int r = 0; r < 4; ++r) {
        const int row = m0 + wm * 128 + mi * 16 + or0 + r;
        #pragma unroll
        for (int ni = 0; ni < 4; ++ni) {
          const int col = n0 + wn * 64 + ni * 16 + fr;
          C[(size_t)row * N + col] = acc[mi][ni][r];
        }
      }
  }
}

// ---------------- row softmax over 2048 bf16, in place ----------------
__global__ __launch_bounds__(256)
void softmax_rows_k(bf16* __restrict__ sc) {
  const size_t row = blockIdx.x;
  bf16* p = sc + row * (size_t)Sn;
  const int t = threadIdx.x;
  unsigned short raw[8];
  *reinterpret_cast<int4*>(raw) = *reinterpret_cast<const int4*>(p + t * 8);
  float x[8];
  float m = -1e30f;
  #pragma unroll
  for (int j = 0; j < 8; ++j) {
    x[j] = __uint_as_float(((unsigned)raw[j]) << 16);
    m = fmaxf(m, x[j]);
  }
  #pragma unroll
  for (int off = 32; off >= 1; off >>= 1) m = fmaxf(m, __shfl_xor(m, off));
  __shared__ float sred[4], ssum[4];
  const int w = t >> 6;
  if ((t & 63) == 0) sred[w] = m;
  __syncthreads();
  m = fmaxf(fmaxf(sred[0], sred[1]), fmaxf(sred[2], sred[3]));
  float e[8], s = 0.f;
  #pragma unroll
  for (int j = 0; j < 8; ++j) { e[j] = __expf(x[j] - m); s += e[j]; }
  #pragma unroll
  for (int off = 32; off >= 1; off >>= 1) s += __shfl_xor(s, off);
  if ((t & 63) == 0) ssum[w] = s;
  __syncthreads();
  s = (ssum[0] + ssum[1]) + (ssum[2] + ssum[3]);
  const float inv = 1.f / s;
  unsigned short o[8];
  #pragma unroll
  for (int j = 0; j < 8; ++j) {
    bf16 hv = __float2bfloat16(e[j] * inv);
    o[j] = *reinterpret_cast<unsigned short*>(&hv);
  }
  *reinterpret_cast<int4*>(p + t * 8) = *reinterpret_cast<const int4*>(o);
}

extern "C" void kernel_launch(void* const* d_in, const int* in_sizes, int n_in,
                              void* d_out, int out_size, void* d_ws, size_t ws_size,
                              hipStream_t stream) {
  const float* q    = (const float*)d_in[0];
  const float* k    = (const float*)d_in[1];
  const float* v1   = (const float*)d_in[2];
  const float* mask = (const float*)d_in[3];
  const float* W1   = (const float*)d_in[4];
  const float* b1   = (const float*)d_in[5];
  const float* W2   = (const float*)d_in[6];
  const float* b2   = (const float*)d_in[7];
  float* out = (float*)d_out;

  const size_t nQKD = (size_t)Bn * Sn * Dn;   // 16,777,216
  char* ws = (char*)d_ws;
  bf16* qkb = (bf16*)ws;                      // [q;k] bf16, 2*nQKD
  bf16* qb  = qkb;
  bf16* kb  = qkb + nQKD;
  bf16* vtb = qkb + 2 * nQKD;                 // [B][D][S]
  bf16* hb  = vtb + nQKD;                     // hidden for [q;k]
  bf16* w1b = hb + 2 * nQKD;
  bf16* w2b = w1b + (size_t)Dn * Dn;
  bf16* scb = w2b + (size_t)Dn * Dn;          // [B][S][S]

  dim3 blk(256);
  const int nQK = (int)nQKD;
  cast_f32_bf16_k<<<dim3(nQK / 4 / 256), blk, 0, stream>>>(q, qb, nQK);
  cast_f32_bf16_k<<<dim3(nQK / 4 / 256), blk, 0, stream>>>(k, kb, nQK);
  cast_f32_bf16_k<<<dim3(Dn * Dn / 4 / 256), blk, 0, stream>>>(W1, w1b, Dn * Dn);
  cast_f32_bf16_k<<<dim3(Dn * Dn / 4 / 256), blk, 0, stream>>>(W2, w2b, Dn * Dn);
  transpose_cast_v_k<<<dim3(Sn / 32, Dn / 32, Bn), blk, 0, stream>>>(v1, vtb);

  const int M2 = 2 * Bn * Sn;  // 32768 rows ([q;k] together)
  dim3 gblk(512);
  // h = [q;k] @ W1^T + b1 : grid 4 x 128 = 512
  gemm256_k<0><<<dim3(4 * (M2 / BM)), gblk, 0, stream>>>(
      qkb, w1b, hb, b1, Dn, Dn, 0, 0, 0, 1.f, 4, M2 / BM);
  // [qp;kp] = h @ W2^T + b2
  gemm256_k<0><<<dim3(4 * (M2 / BM)), gblk, 0, stream>>>(
      hb, w2b, qkb, b2, Dn, Dn, 0, 0, 0, 1.f, 4, M2 / BM);
  // scores = qp @ kp^T * (1/32) + mask : grid 8 x 8 x 8 = 512
  gemm256_k<1><<<dim3(8 * 8 * Bn), gblk, 0, stream>>>(
      qb, kb, scb, mask, Sn, Dn,
      (long long)Sn * Dn, (long long)Sn * Dn, (long long)Sn * Sn, 0.03125f, 8, 8);
  // softmax rows, in place
  softmax_rows_k<<<dim3(Bn * Sn), blk, 0, stream>>>(scb);
  // out = P @ V via VT : grid 4 x 8 x 8 = 256
  gemm256_k<2><<<dim3(4 * 8 * Bn), gblk, 0, stream>>>(
      scb, vtb, out, nullptr, Dn, Sn,
      (long long)Sn * Sn, (long long)Dn * Sn, (long long)Sn * Dn, 1.f, 4, 8);
}

// Round 5
// 376.694 us; speedup vs baseline: 1.0623x; 1.0623x over previous
//
#include <hip/hip_runtime.h>
#include <hip/hip_bf16.h>

typedef __hip_bfloat16 bf16;
typedef __bf16 bf16x8 __attribute__((ext_vector_type(8)));  // MFMA A/B operand
typedef float f32x4 __attribute__((ext_vector_type(4)));

constexpr int Bn = 8, Sn = 2048, Dn = 1024;
constexpr int BM = 256, BN = 256, BK = 64;

// ---------------- cast fp32 -> bf16, vectorized ----------------
__global__ void cast_f32_bf16_k(const float* __restrict__ x, bf16* __restrict__ y, int n) {
  int i = (blockIdx.x * blockDim.x + threadIdx.x) * 4;
  if (i >= n) return;
  float4 f = *reinterpret_cast<const float4*>(x + i);
  bf16 tmp[4] = {__float2bfloat16(f.x), __float2bfloat16(f.y),
                 __float2bfloat16(f.z), __float2bfloat16(f.w)};
  *reinterpret_cast<short4*>(y + i) = *reinterpret_cast<const short4*>(tmp);
}

// ---------------- transpose+cast V: [B][S][D] f32 -> [B][D][S] bf16 ----------------
__global__ void transpose_cast_v_k(const float* __restrict__ v, bf16* __restrict__ vt) {
  __shared__ float tile[32][33];
  const int s0 = blockIdx.x * 32, d0 = blockIdx.y * 32, b = blockIdx.z;
  const float* src = v + (size_t)b * Sn * Dn;
  bf16* dst = vt + (size_t)b * Dn * Sn;
  const int tx = threadIdx.x & 31, ty = threadIdx.x >> 5;
  #pragma unroll
  for (int i = 0; i < 4; ++i) {
    int s = ty + i * 8;
    tile[s][tx] = src[(size_t)(s0 + s) * Dn + d0 + tx];
  }
  __syncthreads();
  #pragma unroll
  for (int i = 0; i < 4; ++i) {
    int d = ty + i * 8;
    dst[(size_t)(d0 + d) * Sn + s0 + tx] = __float2bfloat16(tile[tx][d]);
  }
}

// ---------------- 256x256x64 8-phase GEMM (m201 schedule): C = A @ BT^T ----------------
// LDS element map: A0=0  A1=16384  B0=32768  B1=49152 (each 32KB region, 2 halves)
// All LDS read addresses = per-thread base (kk parity) + compile-time immediate:
//   row & 7 == fr & 7 for every fragment row, so the XOR swizzle mask is a
//   per-thread constant and folds into the base; ms/mi4/buf terms are multiples
//   of 2048 bytes -> ds_read offset immediates. Zero in-loop VALU.
#define SBAR()  asm volatile("s_barrier" ::: "memory")
#define LGKM0() asm volatile("s_waitcnt lgkmcnt(0)" ::: "memory")
#define VM4()   asm volatile("s_waitcnt vmcnt(4)" ::: "memory")
#define VM0()   asm volatile("s_waitcnt vmcnt(0)" ::: "memory")

#define QUAD(ms, ns) do {                                                     \
    __builtin_amdgcn_s_setprio(1);                                            \
    _Pragma("unroll")                                                         \
    for (int kk = 0; kk < 2; ++kk)                                            \
      _Pragma("unroll")                                                       \
      for (int mi4 = 0; mi4 < 4; ++mi4)                                       \
        _Pragma("unroll")                                                     \
        for (int n2 = 0; n2 < 2; ++n2)                                        \
          acc[(ms)*4+mi4][(ns)*2+n2] =                                        \
            __builtin_amdgcn_mfma_f32_16x16x32_bf16(                          \
              aF[mi4][kk], bF[(ns)*2+n2][kk],                                 \
              acc[(ms)*4+mi4][(ns)*2+n2], 0, 0, 0);                           \
    __builtin_amdgcn_s_setprio(0);                                            \
  } while (0)

// buf, ms, ns are compile-time literals at every use site
#define RD_A(buf, ms) do {                                                    \
    _Pragma("unroll")                                                         \
    for (int mi4 = 0; mi4 < 4; ++mi4) {                                       \
      aF[mi4][0] = *reinterpret_cast<const bf16x8*>(                          \
          pA0 + ((buf)*32768 + (ms)*8192 + mi4*2048));                        \
      aF[mi4][1] = *reinterpret_cast<const bf16x8*>(                          \
          pA1 + ((buf)*32768 + (ms)*8192 + mi4*2048));                        \
    }                                                                         \
  } while (0)

#define RD_B(buf, ns) do {                                                    \
    _Pragma("unroll")                                                         \
    for (int j = 0; j < 2; ++j) {                                             \
      bF[(ns)*2+j][0] = *reinterpret_cast<const bf16x8*>(                     \
          pB0 + ((buf)*32768 + (ns)*4096 + j*2048));                          \
      bF[(ns)*2+j][1] = *reinterpret_cast<const bf16x8*>(                     \
          pB1 + ((buf)*32768 + (ns)*4096 + j*2048));                          \
    }                                                                         \
  } while (0)

template<int EPI>
__global__ __launch_bounds__(512, 2)
void gemm256_k(const bf16* __restrict__ A, const bf16* __restrict__ BT,
               void* __restrict__ Cv, const float* __restrict__ aux,
               int N, int K, long long sAz, long long sBz, long long sCz,
               float scale, int gx, int gy)
{
  __shared__ __align__(128) bf16 sh[4 * 16384];   // 128 KiB

  // T1: XCD-aware bijective swizzle (nwg % 8 == 0 for all launches here)
  const int nwg = (int)gridDim.x;
  const int flat = (int)blockIdx.x;
  const int swz = (flat & 7) * (nwg >> 3) + (flat >> 3);
  const int tn = swz % gx;
  const int rem = swz / gx;
  const int tm = rem % gy;
  const int z  = rem / gy;

  const int t = threadIdx.x, w = t >> 6, lane = t & 63;
  const int wm = w >> 2, wn = w & 3;              // 2 x 4 wave grid; wave tile 128x64
  const int fr = lane & 15, kg = lane >> 4;
  const int m0 = tm * BM, n0 = tn * BN;
  const bf16* Abase = A + (size_t)z * sAz + (size_t)m0 * K;
  const bf16* Bbase = BT + (size_t)z * sBz + (size_t)n0 * K;

  f32x4 acc[8][4];
  const f32x4 fz = {0.f, 0.f, 0.f, 0.f};
  #pragma unroll
  for (int i = 0; i < 8; ++i)
    #pragma unroll
    for (int j = 0; j < 4; ++j) acc[i][j] = fz;
  bf16x8 aF[4][2], bF[4][2];

  // ---- hoisted per-thread LDS read bases (swizzle folded in) ----
  const char* shB = (const char*)sh;
  const int m48 = (fr & 3) << 4;                  // XOR mask bits 4-5
  const int m64 = (fr & 4) << 4;                  // XOR mask bit 6
  const int aoff0 = (wm * 128 + fr) * 128 + ((kg * 16) ^ m48) + m64;
  const int boff0 = 65536 + (wn * 64 + fr) * 128 + ((kg * 16) ^ m48) + m64;
  const char* pA0 = shB + aoff0;
  const char* pA1 = shB + (aoff0 ^ 64);           // kk=1 flips bit 6
  const char* pB0 = shB + boff0;
  const char* pB1 = shB + (boff0 ^ 64);

  // ---- hoisted per-thread staging offsets ----
  int gOff[2];
  #pragma unroll
  for (int i = 0; i < 2; ++i) {
    const int slot = i * 512 + w * 64 + lane;
    const int row = slot >> 3;
    const int cb = (slot & 7) ^ (row & 7);        // inverse of read-side XOR swizzle
    gOff[i] = row * K + cb * 8;
  }
  // stage one half-tile (128 rows x 64 cols): uniform base + per-lane offset
  auto stage = [&](int dstElemBase, const bf16* gbase, int half, int kt) {
    const bf16* g0 = gbase + (size_t)(half * 128) * K + (size_t)kt * BK;
    bf16* db = (bf16*)sh + dstElemBase + half * 8192;
    #pragma unroll
    for (int i = 0; i < 2; ++i) {
      __builtin_amdgcn_global_load_lds(
          (__attribute__((address_space(1))) void*)(g0 + gOff[i]),
          (__attribute__((address_space(3))) void*)(db + (i * 512 + w * 64) * 8),
          16, 0, 0);
    }
  };

  const int NT = K / BK;                          // even, >= 4
  // prologue: tile0 full + tile1 B (12 loads/thread); drain tile0
  stage(32768, Bbase, 0, 0); stage(32768, Bbase, 1, 0);
  stage(0,     Abase, 0, 0); stage(0,     Abase, 1, 0);
  stage(49152, Bbase, 0, 1); stage(49152, Bbase, 1, 1);
  VM4();
  SBAR();

  for (int T = 0; T < NT; T += 2) {
    const bool last = (T + 2 >= NT);
    // ph1: tile T quadrant (0,0); stage A1-lo (T+1)
    RD_A(0, 0); RD_B(0, 0);
    stage(16384, Abase, 0, T + 1);
    SBAR(); LGKM0(); QUAD(0, 0); SBAR();
    // ph2: quadrant (0,1); stage A1-hi (T+1)
    RD_B(0, 1);
    stage(16384, Abase, 1, T + 1);
    SBAR(); LGKM0(); QUAD(0, 1); SBAR();
    // ph3: quadrant (1,0); stage B0-lo (T+2)  [B0 free after ph2]
    RD_A(0, 1);
    if (!last) stage(32768, Bbase, 0, T + 2);
    SBAR(); LGKM0(); QUAD(1, 0); SBAR();
    // ph4: quadrant (1,1); stage B0-hi (T+2); drain tile T+1
    if (!last) stage(32768, Bbase, 1, T + 2);
    SBAR(); LGKM0(); QUAD(1, 1);
    if (last) { VM0(); } else { VM4(); }
    SBAR();
    // ph5: tile T+1 quadrant (0,0); stage A0-lo (T+2)  [A0 free after ph3]
    RD_A(1, 0); RD_B(1, 0);
    if (!last) stage(0, Abase, 0, T + 2);
    SBAR(); LGKM0(); QUAD(0, 0); SBAR();
    // ph6: quadrant (0,1); stage A0-hi (T+2)
    RD_B(1, 1);
    if (!last) stage(0, Abase, 1, T + 2);
    SBAR(); LGKM0(); QUAD(0, 1); SBAR();
    // ph7: quadrant (1,0); stage B1-lo (T+3)  [B1 free after ph6]
    RD_A(1, 1);
    if (!last) stage(49152, Bbase, 0, T + 3);
    SBAR(); LGKM0(); QUAD(1, 0); SBAR();
    // ph8: quadrant (1,1); stage B1-hi (T+3); drain tile T+2
    if (!last) stage(49152, Bbase, 1, T + 3);
    SBAR(); LGKM0(); QUAD(1, 1);
    if (!last) { VM4(); }
    SBAR();
  }

  // epilogue: frag (mi,ni): C[m0+wm*128+mi*16+kg*4+r][n0+wn*64+ni*16+fr]
  const int or0 = kg * 4;
  if constexpr (EPI == 0) {
    bf16* C = (bf16*)Cv + (size_t)z * sCz;
    #pragma unroll
    for (int mi = 0; mi < 8; ++mi)
      #pragma unroll
      for (int r = 0; r < 4; ++r) {
        const int row = m0 + wm * 128 + mi * 16 + or0 + r;
        #pragma unroll
        for (int ni = 0; ni < 4; ++ni) {
          const int col = n0 + wn * 64 + ni * 16 + fr;
          C[(size_t)row * N + col] = __float2bfloat16(acc[mi][ni][r] + aux[col]);
        }
      }
  } else if constexpr (EPI == 1) {
    bf16* C = (bf16*)Cv + (size_t)z * sCz;
    #pragma unroll
    for (int mi = 0; mi < 8; ++mi)
      #pragma unroll
      for (int r = 0; r < 4; ++r) {
        const int row = m0 + wm * 128 + mi * 16 + or0 + r;
        #pragma unroll
        for (int ni = 0; ni < 4; ++ni) {
          const int col = n0 + wn * 64 + ni * 16 + fr;
          float v = acc[mi][ni][r] * scale + aux[(size_t)row * N + col];
          C[(size_t)row * N + col] = __float2bfloat16(v);
        }
      }
  } else {
    float* C = (float*)Cv + (size_t)z * sCz;
    #pragma unroll
    for (int mi = 0; mi < 8; ++mi)
      #pragma unroll
      for (int r = 0; r < 4; ++r) {
        const int row = m0 + wm * 128 + mi * 16 + or0 + r;
        #pragma unroll
        for (int ni = 0; ni < 4; ++ni) {
          const int col = n0 + wn * 64 + ni * 16 + fr;
          C[(size_t)row * N + col] = acc[mi][ni][r];
        }
      }
  }
}

// ---------------- row softmax over 2048 bf16, in place ----------------
__global__ __launch_bounds__(256)
void softmax_rows_k(bf16* __restrict__ sc) {
  const size_t row = blockIdx.x;
  bf16* p = sc + row * (size_t)Sn;
  const int t = threadIdx.x;
  unsigned short raw[8];
  *reinterpret_cast<int4*>(raw) = *reinterpret_cast<const int4*>(p + t * 8);
  float x[8];
  float m = -1e30f;
  #pragma unroll
  for (int j = 0; j < 8; ++j) {
    x[j] = __uint_as_float(((unsigned)raw[j]) << 16);
    m = fmaxf(m, x[j]);
  }
  #pragma unroll
  for (int off = 32; off >= 1; off >>= 1) m = fmaxf(m, __shfl_xor(m, off));
  __shared__ float sred[4], ssum[4];
  const int w = t >> 6;
  if ((t & 63) == 0) sred[w] = m;
  __syncthreads();
  m = fmaxf(fmaxf(sred[0], sred[1]), fmaxf(sred[2], sred[3]));
  float e[8], s = 0.f;
  #pragma unroll
  for (int j = 0; j < 8; ++j) { e[j] = __expf(x[j] - m); s += e[j]; }
  #pragma unroll
  for (int off = 32; off >= 1; off >>= 1) s += __shfl_xor(s, off);
  if ((t & 63) == 0) ssum[w] = s;
  __syncthreads();
  s = (ssum[0] + ssum[1]) + (ssum[2] + ssum[3]);
  const float inv = 1.f / s;
  unsigned short o[8];
  #pragma unroll
  for (int j = 0; j < 8; ++j) {
    bf16 hv = __float2bfloat16(e[j] * inv);
    o[j] = *reinterpret_cast<unsigned short*>(&hv);
  }
  *reinterpret_cast<int4*>(p + t * 8) = *reinterpret_cast<const int4*>(o);
}

extern "C" void kernel_launch(void* const* d_in, const int* in_sizes, int n_in,
                              void* d_out, int out_size, void* d_ws, size_t ws_size,
                              hipStream_t stream) {
  const float* q    = (const float*)d_in[0];
  const float* k    = (const float*)d_in[1];
  const float* v1   = (const float*)d_in[2];
  const float* mask = (const float*)d_in[3];
  const float* W1   = (const float*)d_in[4];
  const float* b1   = (const float*)d_in[5];
  const float* W2   = (const float*)d_in[6];
  const float* b2   = (const float*)d_in[7];
  float* out = (float*)d_out;

  const size_t nQKD = (size_t)Bn * Sn * Dn;   // 16,777,216
  char* ws = (char*)d_ws;
  bf16* qkb = (bf16*)ws;                      // [q;k] bf16, 2*nQKD
  bf16* qb  = qkb;
  bf16* kb  = qkb + nQKD;
  bf16* vtb = qkb + 2 * nQKD;                 // [B][D][S]
  bf16* hb  = vtb + nQKD;                     // hidden for [q;k]
  bf16* w1b = hb + 2 * nQKD;
  bf16* w2b = w1b + (size_t)Dn * Dn;
  bf16* scb = w2b + (size_t)Dn * Dn;          // [B][S][S]

  dim3 blk(256);
  const int nQK = (int)nQKD;
  cast_f32_bf16_k<<<dim3(nQK / 4 / 256), blk, 0, stream>>>(q, qb, nQK);
  cast_f32_bf16_k<<<dim3(nQK / 4 / 256), blk, 0, stream>>>(k, kb, nQK);
  cast_f32_bf16_k<<<dim3(Dn * Dn / 4 / 256), blk, 0, stream>>>(W1, w1b, Dn * Dn);
  cast_f32_bf16_k<<<dim3(Dn * Dn / 4 / 256), blk, 0, stream>>>(W2, w2b, Dn * Dn);
  transpose_cast_v_k<<<dim3(Sn / 32, Dn / 32, Bn), blk, 0, stream>>>(v1, vtb);

  const int M2 = 2 * Bn * Sn;  // 32768 rows ([q;k] together)
  dim3 gblk(512);
  // h = [q;k] @ W1^T + b1 : grid 4 x 128 = 512
  gemm256_k<0><<<dim3(4 * (M2 / BM)), gblk, 0, stream>>>(
      qkb, w1b, hb, b1, Dn, Dn, 0, 0, 0, 1.f, 4, M2 / BM);
  // [qp;kp] = h @ W2^T + b2
  gemm256_k<0><<<dim3(4 * (M2 / BM)), gblk, 0, stream>>>(
      hb, w2b, qkb, b2, Dn, Dn, 0, 0, 0, 1.f, 4, M2 / BM);
  // scores = qp @ kp^T * (1/32) + mask : grid 8 x 8 x 8 = 512
  gemm256_k<1><<<dim3(8 * 8 * Bn), gblk, 0, stream>>>(
      qb, kb, scb, mask, Sn, Dn,
      (long long)Sn * Dn, (long long)Sn * Dn, (long long)Sn * Sn, 0.03125f, 8, 8);
  // softmax rows, in place
  softmax_rows_k<<<dim3(Bn * Sn), blk, 0, stream>>>(scb);
  // out = P @ V via VT : grid 4 x 8 x 8 = 256
  gemm256_k<2><<<dim3(4 * 8 * Bn), gblk, 0, stream>>>(
      scb, vtb, out, nullptr, Dn, Sn,
      (long long)Sn * Sn, (long long)Dn * Sn, (long long)Sn * Dn, 1.f, 4, 8);
}